// Round 7
// baseline (138.789 us; speedup 1.0000x reference)
//
#include <hip/hip_runtime.h>

#define B 32
#define M 4096
#define N 8192
#define DC 10
#define NUM_ITERS 8
#define INV_TEMP 100.0f   // 1/TEMP, TEMP=0.01
#define ALPHA 100.0f
#define NB (N * B)        // 262144
#define MB (M * B)        // 131072
#define NEDGE (M * DC)    // 40960
#define CAP 64            // max var degree capacity (Poisson(5): P(>=64) ~ 1e-40)

// Prologue 1: syn sign (M,B), pg[n] = (1-gamma)*prior, zero deg.
__global__ __launch_bounds__(256) void prologue1_kernel(
    const float* __restrict__ syn,    // (B,M)
    const float* __restrict__ prior,  // (N,)
    const float* __restrict__ gamma,  // (N,)
    float* __restrict__ syn_t,        // (M,B)
    float* __restrict__ pg,           // (N,)
    int*   __restrict__ deg)          // (N,)
{
    int idx = blockIdx.x * blockDim.x + threadIdx.x;
    if (idx < MB) {
        int b = idx & 31, m = idx >> 5;
        syn_t[idx] = 1.0f - 2.0f * syn[(size_t)b * M + m];
    }
    if (idx < N) {
        pg[idx]  = (1.0f - gamma[idx]) * prior[idx];
        deg[idx] = 0;
    }
}

// Prologue 2: invert the graph — for each edge e, append e to its variable's
// slot list. Slot order is atomic-arrival-order (fixed within a call; ordering
// noise is the same class as the previous atomicAdd accumulation).
__global__ __launch_bounds__(256) void build_csr_kernel(
    const int* __restrict__ nbrs,   // (M*DC,)
    int* __restrict__ deg,          // (N,)
    int* __restrict__ slots)        // (N,CAP)
{
    int e = blockIdx.x * blockDim.x + threadIdx.x;
    if (e >= NEDGE) return;
    int nb = nbrs[e];
    int slot = atomicAdd(&deg[nb], 1);
    if (slot < CAP) slots[nb * CAP + slot] = e;
}

// Check kernel: one thread per (m,b), b innermost (coalesced). Computes c2v_t
// from llrs_{t-1} (KIND 1) or prior (KIND 0). Writes ONLY c2v — no atomics,
// no llrs writes, no accumulator zeroing. libm tanhf/expf (precision is
// load-bearing: the BP map is chaotic with slope ~ALPHA near v=0).
template <int KIND>
__global__ __launch_bounds__(256) void check_kernel(
    const float* __restrict__ syn_t,  // (M,B) sign form
    const float* __restrict__ prior,  // (N,)
    const int*   __restrict__ nbrs,   // (M,DC)
    const float* __restrict__ Lprev,  // llrs_{t-1} (N,B)  (unused KIND 0)
    float*       __restrict__ c2v)    // (M,DC,B)
{
    int idx = blockIdx.x * blockDim.x + threadIdx.x;  // m*B + b
    if (idx >= MB) return;
    const int b = idx & 31;
    const int m = idx >> 5;

    const int* nr = nbrs + m * DC;
    float* c2vp = c2v + (size_t)(m * DC) * B + b;

    float v[DC];
    if (KIND == 0) {
        #pragma unroll
        for (int i = 0; i < DC; ++i) v[i] = prior[nr[i]];
    } else {
        #pragma unroll
        for (int i = 0; i < DC; ++i)
            v[i] = Lprev[nr[i] * B + b] - c2vp[(size_t)i * B];
    }

    float s[DC], a[DC];
    #pragma unroll
    for (int i = 0; i < DC; ++i) {
        s[i] = tanhf(ALPHA * v[i]);   // smooth_sign (libm precision)
        a[i] = fabsf(v[i]);
    }

    // two smallest |v| and argmin
    float min1 = 3.4e38f, min2 = 3.4e38f;
    int am = 0;
    #pragma unroll
    for (int i = 0; i < DC; ++i) {
        if (a[i] < min1) { min2 = min1; min1 = a[i]; am = i; }
        else if (a[i] < min2) { min2 = a[i]; }
    }

    // prefix/suffix sign products for leave-one-out product
    float pre[DC + 1], suf[DC + 1];
    pre[0] = 1.0f;
    #pragma unroll
    for (int i = 0; i < DC; ++i) pre[i + 1] = pre[i] * s[i];
    suf[DC] = 1.0f;
    #pragma unroll
    for (int i = DC - 1; i >= 0; --i) suf[i] = suf[i + 1] * s[i];

    // softmin sums shifted by min1 (w[am] == 1 exactly)
    float w[DC];
    float se = 0.0f, sae = 0.0f;
    #pragma unroll
    for (int i = 0; i < DC; ++i) {
        w[i] = expf((min1 - a[i]) * INV_TEMP);
        se  += w[i];
        sae += a[i] * w[i];
    }

    // uniform (branchless) min2-shifted sums for the argmin edge's LOO softmin
    float se2 = 0.0f, sae2 = 0.0f;
    #pragma unroll
    for (int j = 0; j < DC; ++j) {
        float e2 = expf((min2 - a[j]) * INV_TEMP);
        e2 = (j != am) ? e2 : 0.0f;
        se2  += e2;
        sae2 += a[j] * e2;
    }
    float me_am = sae2 / se2;

    float ssgn = syn_t[idx];

    #pragma unroll
    for (int i = 0; i < DC; ++i) {
        float me = (i == am) ? me_am : (sae - a[i] * w[i]) / (se - w[i]);
        c2vp[(size_t)i * B] = ssgn * (pre[i] * suf[i + 1]) * me;
    }
}

// Var kernel: one thread per (n,b), b innermost. Gathers incoming c2v via the
// CSR slot list (list is wave-broadcast; c2v reads coalesced in b), applies
// the memory term. Covers ALL n every iteration -> degree-0 vars correct by
// construction (acc=0).
// VK 0: llrs_0 = acc + prior          -> Lcur
// VK 1: llrs_t = acc + pg + g*Lprev   -> Lcur
// VK 2: final  = acc + pg + g*Lprev   -> out (B,N) transposed
template <int VK>
__global__ __launch_bounds__(256) void var_kernel(
    const float* __restrict__ prior,  // (N,)
    const float* __restrict__ pg,     // (N,)
    const float* __restrict__ gamma,  // (N,)
    const int*   __restrict__ deg,    // (N,)
    const int*   __restrict__ slots,  // (N,CAP)
    const float* __restrict__ c2v,    // (M,DC,B)
    const float* __restrict__ Lprev,  // (N,B) (unused VK 0)
    float*       __restrict__ Lcur,   // (N,B) (unused VK 2)
    float*       __restrict__ out)    // (B,N) (VK 2 only)
{
    int idx = blockIdx.x * blockDim.x + threadIdx.x;  // n*B + b
    if (idx >= NB) return;
    const int b = idx & 31;
    const int n = idx >> 5;

    int d = deg[n];
    if (d > CAP) d = CAP;
    const int* sl = slots + n * CAP;

    float acc = 0.0f;
    for (int j = 0; j < d; ++j) {
        int e = sl[j];                 // broadcast within 32-lane group
        acc += c2v[(size_t)e * B + b]; // coalesced in b
    }

    float l;
    if (VK == 0) {
        l = acc + prior[n];
    } else {
        l = acc + pg[n] + gamma[n] * Lprev[idx];
    }

    if (VK == 2) {
        out[(size_t)b * N + n] = l;    // one-time transposed write
    } else {
        Lcur[idx] = l;
    }
}

extern "C" void kernel_launch(void* const* d_in, const int* in_sizes, int n_in,
                              void* d_out, int out_size, void* d_ws, size_t ws_size,
                              hipStream_t stream) {
    const float* syn   = (const float*)d_in[0];   // (B,M)
    const float* prior = (const float*)d_in[1];   // (N,)
    const float* gamma = (const float*)d_in[2];   // (N,)
    const int*   nbrs  = (const int*)d_in[3];     // (M,DC)
    float* out = (float*)d_out;                   // (B,N)

    float* ws = (float*)d_ws;
    float* L[2]  = { ws, ws + NB };               // llrs ping-pong
    float* c2v   = ws + 2 * (size_t)NB;           // M*DC*B
    float* syn_t = c2v + (size_t)NEDGE * B;       // M*B
    float* pg    = syn_t + MB;                    // N
    int*   deg   = (int*)(pg + N);                // N
    int*   slots = deg + N;                       // N*CAP

    dim3 blk(256);
    dim3 pgrid1((MB + 255) / 256);
    dim3 egrid((NEDGE + 255) / 256);
    dim3 cgrid((MB + 255) / 256);
    dim3 vgrid((NB + 255) / 256);

    prologue1_kernel<<<pgrid1, blk, 0, stream>>>(syn, prior, gamma, syn_t, pg, deg);
    build_csr_kernel<<<egrid, blk, 0, stream>>>(nbrs, deg, slots);

    for (int t = 0; t < NUM_ITERS; ++t) {
        float* Lp = L[(t + 1) & 1];   // llrs_{t-1} (parity of t-1)
        float* Lc = L[t & 1];         // llrs_t
        if (t == 0) {
            check_kernel<0><<<cgrid, blk, 0, stream>>>(syn_t, prior, nbrs, nullptr, c2v);
            var_kernel<0><<<vgrid, blk, 0, stream>>>(prior, pg, gamma, deg, slots, c2v,
                                                     nullptr, Lc, nullptr);
        } else if (t < NUM_ITERS - 1) {
            check_kernel<1><<<cgrid, blk, 0, stream>>>(syn_t, prior, nbrs, Lp, c2v);
            var_kernel<1><<<vgrid, blk, 0, stream>>>(prior, pg, gamma, deg, slots, c2v,
                                                     Lp, Lc, nullptr);
        } else {
            check_kernel<1><<<cgrid, blk, 0, stream>>>(syn_t, prior, nbrs, Lp, c2v);
            var_kernel<2><<<vgrid, blk, 0, stream>>>(prior, pg, gamma, deg, slots, c2v,
                                                     Lp, nullptr, out);
        }
    }
}

// Round 8
// 85.831 us; speedup vs baseline: 1.6170x; 1.6170x over previous
//
#include <hip/hip_runtime.h>

#define B 32
#define M 4096
#define N 8192
#define DC 10
#define NUM_ITERS 8
#define INV_TEMP 100.0f   // 1/TEMP, TEMP=0.01
#define ALPHA 100.0f
#define NB (N * B)        // 262144
#define MB (M * B)        // 131072

// Prologue: zero accum A0, init BOTH llrs buffers to prior (degree-0 variables:
// their llrs_t == prior for all t and final_kernel reads all n), build syn sign
// (M,B), build pg[n] = (1-gamma)*prior.
__global__ __launch_bounds__(256) void prologue_kernel(
    const float* __restrict__ syn,    // (B,M)
    const float* __restrict__ prior,  // (N,)
    const float* __restrict__ gamma,  // (N,)
    float* __restrict__ accumA,       // (N,B)
    float* __restrict__ L0,           // (N,B)
    float* __restrict__ L1,           // (N,B)
    float* __restrict__ syn_t,        // (M,B)
    float* __restrict__ pg)           // (N,)
{
    int idx = blockIdx.x * blockDim.x + threadIdx.x;
    if (idx < NB) {
        float p = prior[idx >> 5];
        accumA[idx] = 0.0f;
        L0[idx] = p;
        L1[idx] = p;
    }
    if (idx < MB) {
        int b = idx & 31, m = idx >> 5;
        syn_t[idx] = 1.0f - 2.0f * syn[(size_t)b * M + m];
    }
    if (idx < N) pg[idx] = (1.0f - gamma[idx]) * prior[idx];
}

// Fused check+var kernel (R5 structure). One thread per (m,b), b innermost.
// R8 change (isolated): hardware transcendentals. R4 proved the old precision
// fear was unfounded (R3 __expf and R4 libm failed with bit-identical absmax
// = the degree-0 bug, not fast-math); R5 passes with 6x threshold headroom.
// tanh(a*v) = copysign((1-t)/(1+t), v), t = __expf(-2a|v|): one v_exp_f32,
// exactly +-1.0 in the saturated region, smooth elsewhere.
// KIND 0: t=0   v2c = prior[nb]
// KIND 1: t=1   llrs_0 = R + prior; v2c = llrs_0 - c2v; write Lnew
// KIND 2: t>=2  llrs   = R + pg + gamma*Lold; v2c = llrs - c2v; write Lnew
template <int KIND>
__global__ __launch_bounds__(256) void check_kernel(
    const float* __restrict__ syn_t,  // (M,B) sign form
    const float* __restrict__ prior,  // (N,)
    const float* __restrict__ pg,     // (N,)
    const float* __restrict__ gamma,  // (N,)
    const int*   __restrict__ nbrs,   // (M,DC)
    const float* __restrict__ R,      // accum_{t-1} (N,B)
    float*       __restrict__ W,      // accum_t (N,B), pre-zeroed
    float*       __restrict__ Z,      // accum buffer zeroed here for t+1
    const float* __restrict__ Lold,   // llrs_{t-2} (N,B)
    float*       __restrict__ Lnew,   // llrs_{t-1} (N,B)
    float*       __restrict__ c2v)    // (M,DC,B)
{
    int idx = blockIdx.x * blockDim.x + threadIdx.x;  // m*B + b
    if (idx >= MB) return;
    const int b = idx & 31;
    const int m = idx >> 5;

    // zero next iteration's accumulator (2 elements per thread)
    Z[idx] = 0.0f;
    Z[idx + MB] = 0.0f;

    const int* nr = nbrs + m * DC;
    float* c2vp = c2v + (size_t)(m * DC) * B + b;

    int nb[DC];
    #pragma unroll
    for (int i = 0; i < DC; ++i) nb[i] = nr[i];   // broadcast across lanes

    float v[DC];
    if (KIND == 0) {
        #pragma unroll
        for (int i = 0; i < DC; ++i) v[i] = prior[nb[i]];
    } else if (KIND == 1) {
        #pragma unroll
        for (int i = 0; i < DC; ++i) {
            int g = nb[i] * B + b;
            float l = R[g] + prior[nb[i]];
            Lnew[g] = l;                           // redundant identical writes: benign
            v[i] = l - c2vp[(size_t)i * B];
        }
    } else {
        #pragma unroll
        for (int i = 0; i < DC; ++i) {
            int g = nb[i] * B + b;
            float l = R[g] + pg[nb[i]] + gamma[nb[i]] * Lold[g];
            Lnew[g] = l;
            v[i] = l - c2vp[(size_t)i * B];
        }
    }

    float s[DC], a[DC];
    #pragma unroll
    for (int i = 0; i < DC; ++i) {
        a[i] = fabsf(v[i]);
        float t = __expf(-2.0f * ALPHA * a[i]);          // v_exp_f32
        float mag = (1.0f - t) / (1.0f + t);             // tanh(ALPHA*|v|)
        s[i] = copysignf(mag, v[i]);
    }

    // two smallest |v| and argmin
    float min1 = 3.4e38f, min2 = 3.4e38f;
    int am = 0;
    #pragma unroll
    for (int i = 0; i < DC; ++i) {
        if (a[i] < min1) { min2 = min1; min1 = a[i]; am = i; }
        else if (a[i] < min2) { min2 = a[i]; }
    }

    // prefix/suffix sign products for leave-one-out product
    float pre[DC + 1], suf[DC + 1];
    pre[0] = 1.0f;
    #pragma unroll
    for (int i = 0; i < DC; ++i) pre[i + 1] = pre[i] * s[i];
    suf[DC] = 1.0f;
    #pragma unroll
    for (int i = DC - 1; i >= 0; --i) suf[i] = suf[i + 1] * s[i];

    // softmin sums shifted by min1 (w[am] == 1 exactly; args <= 0, __expf
    // underflows cleanly to 0 for very negative args)
    float w[DC];
    float se = 0.0f, sae = 0.0f;
    #pragma unroll
    for (int i = 0; i < DC; ++i) {
        w[i] = __expf((min1 - a[i]) * INV_TEMP);
        se  += w[i];
        sae += a[i] * w[i];
    }

    // uniform (branchless) min2-shifted sums for the argmin edge's LOO softmin
    float se2 = 0.0f, sae2 = 0.0f;
    #pragma unroll
    for (int j = 0; j < DC; ++j) {
        float e2 = __expf((min2 - a[j]) * INV_TEMP);
        e2 = (j != am) ? e2 : 0.0f;
        se2  += e2;
        sae2 += a[j] * e2;
    }
    float me_am = sae2 / se2;

    float ssgn = syn_t[idx];

    #pragma unroll
    for (int i = 0; i < DC; ++i) {
        float me = (i == am) ? me_am : (sae - a[i] * w[i]) / (se - w[i]);
        float out = ssgn * (pre[i] * suf[i + 1]) * me;
        c2vp[(size_t)i * B] = out;
        atomicAdd(&W[nb[i] * B + b], out);
    }
}

// Epilogue: llrs_7 = accum_7 + pg + gamma*llrs_6, written transposed to d_out (B,N).
__global__ __launch_bounds__(256) void final_kernel(
    const float* __restrict__ R,     // accum_7 (N,B)
    const float* __restrict__ pg,    // (N,)
    const float* __restrict__ gamma, // (N,)
    const float* __restrict__ Lold,  // llrs_6 (N,B)
    float*       __restrict__ out)   // (B,N)
{
    int idx = blockIdx.x * blockDim.x + threadIdx.x;  // b*N + n (write-coalesced)
    if (idx >= NB) return;
    int n = idx & (N - 1);
    int b = idx >> 13;
    int goff = n * B + b;
    out[idx] = R[goff] + pg[n] + gamma[n] * Lold[goff];
}

extern "C" void kernel_launch(void* const* d_in, const int* in_sizes, int n_in,
                              void* d_out, int out_size, void* d_ws, size_t ws_size,
                              hipStream_t stream) {
    const float* syn   = (const float*)d_in[0];   // (B,M)
    const float* prior = (const float*)d_in[1];   // (N,)
    const float* gamma = (const float*)d_in[2];   // (N,)
    const int*   nbrs  = (const int*)d_in[3];     // (M,DC)
    float* out = (float*)d_out;                   // (B,N)

    float* ws = (float*)d_ws;
    float* A[3] = { ws, ws + NB, ws + 2 * (size_t)NB };          // accum rotation
    float* L[2] = { ws + 3 * (size_t)NB, ws + 4 * (size_t)NB };  // llrs double buffer
    float* c2v   = ws + 5 * (size_t)NB;                          // M*DC*B
    float* syn_t = c2v + (size_t)M * DC * B;                     // M*B
    float* pg    = syn_t + MB;                                   // N

    dim3 blk256(256);
    dim3 pgrid((NB + 255) / 256);
    dim3 cgrid((MB + 255) / 256);

    prologue_kernel<<<pgrid, blk256, 0, stream>>>(syn, prior, gamma, A[0], L[0], L[1], syn_t, pg);

    for (int t = 0; t < NUM_ITERS; ++t) {
        float* Rb = A[(t + 2) % 3];
        float* Wb = A[t % 3];
        float* Zb = A[(t + 1) % 3];
        float* Lo = L[t & 1];          // llrs_{t-2}
        float* Ln = L[(t + 1) & 1];    // llrs_{t-1}
        if (t == 0) {
            check_kernel<0><<<cgrid, blk256, 0, stream>>>(syn_t, prior, pg, gamma, nbrs,
                                                          nullptr, Wb, Zb, nullptr, nullptr, c2v);
        } else if (t == 1) {
            check_kernel<1><<<cgrid, blk256, 0, stream>>>(syn_t, prior, pg, gamma, nbrs,
                                                          Rb, Wb, Zb, nullptr, Ln, c2v);
        } else {
            check_kernel<2><<<cgrid, blk256, 0, stream>>>(syn_t, prior, pg, gamma, nbrs,
                                                          Rb, Wb, Zb, Lo, Ln, c2v);
        }
    }
    // after t=7: accum_7 = A[7%3] = A[1], llrs_6 = L[(7+1)&1] = L[0]
    final_kernel<<<pgrid, blk256, 0, stream>>>(A[1], pg, gamma, L[0], out);
}